// Round 5
// baseline (60.821 us; speedup 1.0000x reference)
//
#include <hip/hip_runtime.h>

#define BOUNDV 2.0f
#define MIN_NEAR 0.05f
#define TCOARSE 128
#define NIMP 128
#define INV128 0.0078125f
#define INV256 0.00390625f

__global__ __launch_bounds__(256) void nerf_sample_pdf_kernel(
    const float* __restrict__ rays_o,
    const float* __restrict__ rays_d,
    const float* __restrict__ weights,
    float* __restrict__ out,
    int n_rays)
{
    const int tid = threadIdx.x;
    const int l   = tid & 15;                     // lane within 16-lane group (one ray/group)
    const int ray = blockIdx.x * 16 + (tid >> 4);
    if (ray >= n_rays) return;

    // ---- AABB slab test (all 16 lanes of the group redundantly; 4 distinct rays/wave) ----
    const float* ro = rays_o + (size_t)ray * 3;
    const float* rd = rays_d + (size_t)ray * 3;
    float near = -1e30f, far = 1e30f;
    #pragma unroll
    for (int c = 0; c < 3; ++c) {
        float o = ro[c];
        float d = rd[c] + 1e-15f;
        float r = __builtin_amdgcn_rcpf(d);
        float t0 = (-BOUNDV - o) * r;
        float t1 = ( BOUNDV - o) * r;
        near = fmaxf(near, fminf(t0, t1));
        far  = fminf(far,  fmaxf(t0, t1));
    }
    if (far < near) { near = 1e9f; far = 1e9f; }
    near = fmaxf(near, MIN_NEAR);
    float span = far - near;
    float bw   = span * INV128;

    // ---- 8 weights/lane: two float4 loads + in-lane prefix sums ----
    const float* wp = weights + (size_t)ray * TCOARSE + 8 * l;
    float4 wa = *reinterpret_cast<const float4*>(wp);
    float4 wb = *reinterpret_cast<const float4*>(wp + 4);
    float q[8];
    q[0] = wa.x + 1e-5f;
    q[1] = q[0] + (wa.y + 1e-5f);
    q[2] = q[1] + (wa.z + 1e-5f);
    q[3] = q[2] + (wa.w + 1e-5f);
    q[4] = q[3] + (wb.x + 1e-5f);
    q[5] = q[4] + (wb.y + 1e-5f);
    q[6] = q[5] + (wb.z + 1e-5f);
    q[7] = q[6] + (wb.w + 1e-5f);
    float s8 = q[7];

    // ---- 16-lane inclusive scan (4 DPP row_shr steps; DPP row == 16 lanes) ----
    float S = s8;
    {
        int m;
        m = __builtin_amdgcn_update_dpp(0, __float_as_int(S), 0x111, 0xf, 0xf, true);
        S += __int_as_float(m);
        m = __builtin_amdgcn_update_dpp(0, __float_as_int(S), 0x112, 0xf, 0xf, true);
        S += __int_as_float(m);
        m = __builtin_amdgcn_update_dpp(0, __float_as_int(S), 0x114, 0xf, 0xf, true);
        S += __int_as_float(m);
        m = __builtin_amdgcn_update_dpp(0, __float_as_int(S), 0x118, 0xf, 0xf, true);
        S += __int_as_float(m);
    }
    // ray total = lane 15 of this 16-group: BitMode swizzle src = (i&0x10)|0xF
    float total = __int_as_float(
        __builtin_amdgcn_ds_swizzle(__float_as_int(S), 0x1F0));
    float it      = __builtin_amdgcn_rcpf(total);
    float excl_it = (S - s8) * it;                // cdf value at this lane's first edge

    // ---- walk 8 owned intervals: closed-form inverse searchsorted + affine eval ----
    float c  = excl_it;
    float kf = ceilf(fmaf(128.0f, c, -0.5f));     // first sample index >= c  (>= -0.0)
    float bb = fmaf(bw, (float)(8 * l), near);    // bins[8l]
    float* orow = out + (size_t)ray * NIMP;

    #pragma unroll
    for (int j = 0; j < 8; ++j) {
        float cn  = fmaf(q[j], it, excl_it);      // next cdf edge
        float knf = fminf(ceilf(fmaf(128.0f, cn, -0.5f)), 128.0f);
        float d   = cn - c;
        float r   = (d < 1e-5f) ? 1.0f : __builtin_amdgcn_rcpf(d);
        float sl  = bw * r;
        float ic  = fmaf(-c, sl, bb);
        int k  = (int)kf;
        int kn = (int)knf;
        if (k < kn) {                             // typ. 0-2 samples, max 3 (total>51 guard)
            float u = fmaf(kf, INV128, INV256);
            orow[k] = fmaf(u, sl, ic);
            if (k + 1 < kn) {
                orow[k + 1] = fmaf(u + INV128, sl, ic);
                for (int s = k + 2; s < kn; ++s)  // essentially never taken
                    orow[s] = fmaf(fmaf((float)s, INV128, INV256), sl, ic);
            }
        }
        c = cn; kf = knf; bb += bw;
    }
}

extern "C" void kernel_launch(void* const* d_in, const int* in_sizes, int n_in,
                              void* d_out, int out_size, void* d_ws, size_t ws_size,
                              hipStream_t stream) {
    const float* rays_o  = (const float*)d_in[0];
    const float* rays_d  = (const float*)d_in[1];
    const float* weights = (const float*)d_in[2];
    float* out = (float*)d_out;

    int n_rays = in_sizes[0] / 3;
    int blocks = (n_rays + 15) / 16;              // 16 rays per 256-thread block
    hipLaunchKernelGGL(nerf_sample_pdf_kernel, dim3(blocks), dim3(256), 0, stream,
                       rays_o, rays_d, weights, out, n_rays);
}

// Round 6
// 26.041 us; speedup vs baseline: 2.3356x; 2.3356x over previous
//
#include <hip/hip_runtime.h>

#define BOUNDV 2.0f
#define MIN_NEAR 0.05f
#define TCOARSE 128
#define NIMP 128
#define INV128 0.0078125f
#define INV256 0.00390625f

__global__ __launch_bounds__(256) void nerf_sample_pdf_kernel(
    const float* __restrict__ rays_o,
    const float* __restrict__ rays_d,
    const float* __restrict__ weights,
    float* __restrict__ out,
    int n_rays)
{
    __shared__ float stg[4][512];                 // per-wave 2KB staging (4 rays x 128)

    const int tid  = threadIdx.x;
    const int lane = tid & 63;
    const int wv   = tid >> 6;
    const int grp  = (tid >> 4) & 3;              // 16-lane group within wave = ray slot
    const int l16  = tid & 15;
    const int ray  = blockIdx.x * 16 + (tid >> 4);

    if (ray < n_rays) {
        // ---- AABB slab test (16 lanes redundant; 4 distinct rays/wave) ----
        const float* ro = rays_o + (size_t)ray * 3;
        const float* rd = rays_d + (size_t)ray * 3;
        float near = -1e30f, far = 1e30f;
        #pragma unroll
        for (int c = 0; c < 3; ++c) {
            float o = ro[c];
            float d = rd[c] + 1e-15f;
            float r = __builtin_amdgcn_rcpf(d);
            float t0 = (-BOUNDV - o) * r;
            float t1 = ( BOUNDV - o) * r;
            near = fmaxf(near, fminf(t0, t1));
            far  = fminf(far,  fmaxf(t0, t1));
        }
        if (far < near) { near = 1e9f; far = 1e9f; }
        near = fmaxf(near, MIN_NEAR);
        float span = far - near;
        float bw   = span * INV128;

        // ---- 8 weights/lane: two float4 loads + in-lane prefix sums ----
        const float* wp = weights + (size_t)ray * TCOARSE + 8 * l16;
        float4 wa = *reinterpret_cast<const float4*>(wp);
        float4 wb = *reinterpret_cast<const float4*>(wp + 4);
        float q[8];
        q[0] = wa.x + 1e-5f;
        q[1] = q[0] + (wa.y + 1e-5f);
        q[2] = q[1] + (wa.z + 1e-5f);
        q[3] = q[2] + (wa.w + 1e-5f);
        q[4] = q[3] + (wb.x + 1e-5f);
        q[5] = q[4] + (wb.y + 1e-5f);
        q[6] = q[5] + (wb.z + 1e-5f);
        q[7] = q[6] + (wb.w + 1e-5f);
        float s8 = q[7];

        // ---- 16-lane inclusive scan (4 DPP row_shr steps) ----
        float S = s8;
        {
            int m;
            m = __builtin_amdgcn_update_dpp(0, __float_as_int(S), 0x111, 0xf, 0xf, true);
            S += __int_as_float(m);
            m = __builtin_amdgcn_update_dpp(0, __float_as_int(S), 0x112, 0xf, 0xf, true);
            S += __int_as_float(m);
            m = __builtin_amdgcn_update_dpp(0, __float_as_int(S), 0x114, 0xf, 0xf, true);
            S += __int_as_float(m);
            m = __builtin_amdgcn_update_dpp(0, __float_as_int(S), 0x118, 0xf, 0xf, true);
            S += __int_as_float(m);
        }
        // ray total = lane 15 of this 16-group (BitMode: src = (lane & 0x10) | 0xF)
        float total = __int_as_float(
            __builtin_amdgcn_ds_swizzle(__float_as_int(S), 0x1F0));
        float it      = __builtin_amdgcn_rcpf(total);
        float excl_it = (S - s8) * it;            // cdf at this lane's first edge

        // ---- walk 8 owned intervals; scatter samples into LDS row ----
        float* srow = &stg[wv][grp * 128];
        float c  = excl_it;
        float kf = ceilf(fmaf(128.0f, c, -0.5f));
        float bb = fmaf(bw, (float)(8 * l16), near);

        #pragma unroll
        for (int j = 0; j < 8; ++j) {
            float cn  = fmaf(q[j], it, excl_it);
            float knf = fminf(ceilf(fmaf(128.0f, cn, -0.5f)), 128.0f);
            float d   = cn - c;
            float r   = (d < 1e-5f) ? 1.0f : __builtin_amdgcn_rcpf(d);
            float sl  = bw * r;
            float ic  = fmaf(-c, sl, bb);
            int k  = (int)kf;
            int kn = (int)knf;
            if (k < kn) {                          // typ. 0-2 samples, max ~3
                float u = fmaf(kf, INV128, INV256);
                srow[k] = fmaf(u, sl, ic);
                if (k + 1 < kn) {
                    srow[k + 1] = fmaf(u + INV128, sl, ic);
                    for (int s = k + 2; s < kn; ++s)   // essentially never taken
                        srow[s] = fmaf(fmaf((float)s, INV128, INV256), sl, ic);
                }
            }
            c = cn; kf = knf; bb += bw;
        }
    }

    // DS ops are in-order per wave; readback below stays within this wave's
    // region, so no __syncthreads needed — just a scheduling fence.
    __builtin_amdgcn_wave_barrier();

    // ---- coalesced readback + store: wave's 4 rays = contiguous 2KB ----
    int wray = blockIdx.x * 16 + wv * 4;
    if (wray + 4 <= n_rays) {
        const float4* sf = reinterpret_cast<const float4*>(&stg[wv][0]);
        float4 v0 = sf[lane];
        float4 v1 = sf[64 + lane];
        float* ob = out + (size_t)wray * NIMP;
        reinterpret_cast<float4*>(ob)[lane]      = v0;
        reinterpret_cast<float4*>(ob)[64 + lane] = v1;
    }
}

extern "C" void kernel_launch(void* const* d_in, const int* in_sizes, int n_in,
                              void* d_out, int out_size, void* d_ws, size_t ws_size,
                              hipStream_t stream) {
    const float* rays_o  = (const float*)d_in[0];
    const float* rays_d  = (const float*)d_in[1];
    const float* weights = (const float*)d_in[2];
    float* out = (float*)d_out;

    int n_rays = in_sizes[0] / 3;
    int blocks = (n_rays + 15) / 16;              // 16 rays per 256-thread block
    hipLaunchKernelGGL(nerf_sample_pdf_kernel, dim3(blocks), dim3(256), 0, stream,
                       rays_o, rays_d, weights, out, n_rays);
}